// Round 9
// baseline (135.719 us; speedup 1.0000x reference)
//
#include <hip/hip_runtime.h>
#include <math.h>

// Problem constants: B=32, F=2048, hw=49, A=1.
#define BB    32
#define FF    2048
#define HW    49
#define ROWS  (BB * FF)
#define DPAD  64
#define SPLIT 8
#define GSTEP 32
#define GHALF (FF / SPLIT)               // 256
#define NSTEP (GHALF / GSTEP)            // 8

typedef float f32x16 __attribute__((ext_vector_type(16)));
typedef _Float16 f16x8 __attribute__((ext_vector_type(8)));
typedef short s16x8 __attribute__((ext_vector_type(8)));

// exp2 via the amdgcn builtin -> single v_exp_f32, compiler-managed hazards.
__device__ inline float exp2_fast(float x) {
    return __builtin_amdgcn_exp2f(x);
}

// fp32 -> fp16 hi + fp16 lo (RNE), packed (hi<<16)|lo. Combined rel err ~2^-22.
__device__ inline unsigned f16pack(float v) {
    _Float16 h = (_Float16)v;
    _Float16 l = (_Float16)(v - (float)h);
    unsigned hb = (unsigned)__builtin_bit_cast(unsigned short, h);
    unsigned lb = (unsigned)__builtin_bit_cast(unsigned short, l);
    return (hb << 16) | lb;
}

__device__ inline void unpack8(uint4 a, uint4 b, f16x8& h, f16x8& l) {
    unsigned w[8] = {a.x, a.y, a.z, a.w, b.x, b.y, b.z, b.w};
    s16x8 hs, ls;
    #pragma unroll
    for (int i = 0; i < 8; ++i) {
        hs[i] = (short)(w[i] >> 16);
        ls[i] = (short)(w[i] & 0xFFFFu);
    }
    h = __builtin_bit_cast(f16x8, hs);
    l = __builtin_bit_cast(f16x8, ls);
}

// ---------------------------------------------------------------------------
// prep: M[j,d] = sum_e Wq[e,j] Wk[e,d] * log2(e)/7 -> Mtpk[d][j] (fp16 hi/lo)
//       u[d]   = sum_e Wv[e,d] * Wout[e]
// Scores come out in the log2 domain; softmax probs = exp2(s) = e^(q.k/7).
// ---------------------------------------------------------------------------
__global__ __launch_bounds__(256) void prep_kernel(
    const float* __restrict__ Wqkv, const float* __restrict__ Wout,
    unsigned* __restrict__ Mtpk, float* __restrict__ u)
{
    __shared__ float W2[98][52];
    const int tid = threadIdx.x;
    if (blockIdx.x < 16) {
        for (int i = tid; i < 98 * 52; i += 256) {
            int e = i / 52, j = i - e * 52;
            W2[e][j] = (j < HW) ? Wqkv[e * HW + j] : 0.f;
        }
        __syncthreads();
        const int d = blockIdx.x * 4 + (tid >> 6);
        const int j = tid & 63;
        float s = 0.f;
        if (d < HW && j < HW) {
            for (int e = 0; e < HW; ++e) s = fmaf(W2[e][j], W2[49 + e][d], s);
            s *= 0.2060992915555662f;      // log2(e) / 7
        }
        Mtpk[d * 64 + j] = f16pack(s);
    } else {
        if (tid < 64) {
            float s = 0.f;
            if (tid < HW)
                for (int e = 0; e < HW; ++e)
                    s = fmaf(Wqkv[(98 + e) * HW + tid], Wout[e], s);
            u[tid] = s;
        }
    }
}

// ---------------------------------------------------------------------------
// xymm: per 128 rows: coalesced x load via LDS bounce, fp16 hi/lo panels
// xh/xl, w = x.u, y = x.M (3-MFMA fp16 hi/lo) -> packed u32 panel ypk.
// dt processed sequentially (Mt frags reloaded) to keep VGPR pressure low.
// ---------------------------------------------------------------------------
__global__ __launch_bounds__(256) void xymm_kernel(
    const float* __restrict__ x, const unsigned* __restrict__ Mtpk,
    const float* __restrict__ u,
    unsigned short* __restrict__ xh, unsigned short* __restrict__ xl,
    unsigned* __restrict__ ypk, float* __restrict__ wv)
{
    __shared__ float xsh[128 * HW];
    __shared__ float ush[64];
    const int tid = threadIdx.x, lane = tid & 63, wid = tid >> 6;
    const int col = lane & 31, half = lane >> 5;
    if (tid < 64) ush[tid] = u[tid];

    {
        const float* xb = x + (size_t)blockIdx.x * 128 * HW;
        for (int i = tid; i < 128 * HW; i += 256) xsh[i] = xb[i];
    }
    __syncthreads();

    const int rloc = wid * 32 + col;
    const int row = blockIdx.x * 128 + rloc;

    f16x8 ah[4], al[4];
    float wp = 0.f;
    #pragma unroll
    for (int ks = 0; ks < 4; ++ks) {
        s16x8 hs, ls;
        #pragma unroll
        for (int i = 0; i < 8; ++i) {
            int d = ks * 16 + half * 8 + i;
            float t = (d < HW) ? xsh[rloc * HW + d] : 0.f;
            wp = fmaf(t, ush[d], wp);
            _Float16 h = (_Float16)t;
            _Float16 l = (_Float16)(t - (float)h);
            hs[i] = __builtin_bit_cast(short, h);
            ls[i] = __builtin_bit_cast(short, l);
        }
        ah[ks] = __builtin_bit_cast(f16x8, hs);
        al[ks] = __builtin_bit_cast(f16x8, ls);
        const size_t o = (size_t)row * DPAD + ks * 16 + half * 8;
        *(f16x8*)(xh + o) = ah[ks];
        *(f16x8*)(xl + o) = al[ks];
    }
    wp += __shfl_xor(wp, 32);
    if (half == 0) wv[row] = wp;

    const int r0 = blockIdx.x * 128 + wid * 32;
    for (int dt = 0; dt < 2; ++dt) {
        f16x8 mh[4], ml[4];
        #pragma unroll
        for (int ks = 0; ks < 4; ++ks) {
            const unsigned* mp = Mtpk + (dt * 32 + col) * 64 + ks * 16 + half * 8;
            unpack8(*(const uint4*)mp, *(const uint4*)(mp + 4), mh[ks], ml[ks]);
        }
        f32x16 acc;
        #pragma unroll
        for (int i = 0; i < 16; ++i) acc[i] = 0.f;
        #pragma unroll
        for (int ks = 0; ks < 4; ++ks) {
            acc = __builtin_amdgcn_mfma_f32_32x32x16_f16(ah[ks], ml[ks], acc, 0, 0, 0);
            acc = __builtin_amdgcn_mfma_f32_32x32x16_f16(al[ks], mh[ks], acc, 0, 0, 0);
            acc = __builtin_amdgcn_mfma_f32_32x32x16_f16(ah[ks], mh[ks], acc, 0, 0, 0);
        }
        #pragma unroll
        for (int reg = 0; reg < 16; ++reg) {
            int drow = (reg & 3) + 8 * (reg >> 2) + 4 * half;
            ypk[(size_t)(r0 + drow) * DPAD + dt * 32 + col] = f16pack(acc[reg]);
        }
    }
}

// ---------------------------------------------------------------------------
// attn: scores(log2-domain) = y . x^T (3-MFMA fp16 hi/lo), no-max softmax
// via v_exp_f32, scalar value w. Block: 4 waves x 32 f-cols, GHALF=256
// g-rows. K-tile 32 rows (8 KB) double-buffered -> 17.4 KB LDS -> 8
// blocks/CU at VGPR<=64. Per-XCD b-major sweep: ~256 resident logical ids
// span ~2 b-panels (~2 MB) -> L2-resident.
// ---------------------------------------------------------------------------
__global__ __launch_bounds__(256, 4) void attn_kernel(
    const unsigned short* __restrict__ xh, const unsigned short* __restrict__ xl,
    const unsigned* __restrict__ ypk, const float* __restrict__ wv,
    float* __restrict__ partL, float* __restrict__ partA)
{
    __shared__ __align__(16) unsigned char Kt[2][GSTEP * 256];   // 2 x 8 KB
    __shared__ __align__(16) float wssh[GHALF];                  // 1 KB

    // XCD-chunked swizzle: 4096 blocks, 512 logical per XCD, b-major:
    // 128 blocks per b -> resident window (~256 ids) spans ~2 panels.
    const int bid = blockIdx.x;
    const int L = (bid & 7) * 512 + (bid >> 3);
    const int b    = L >> 7;        // 0..31
    const int r127 = L & 127;
    const int ftg  = r127 >> 3;     // 0..15
    const int sp   = r127 & 7;      // 0..7

    const int tid  = threadIdx.x;
    const int lane = tid & 63;
    const int wid  = tid >> 6;
    const int col  = lane & 31;
    const int half = lane >> 5;
    const int fblk0  = ftg * 128 + wid * 32;
    const int gstart = sp * GHALF;
    const size_t bq = (size_t)b * FF;

    // hoist y fragments (B operand, col = fblk0+col), unpack hi/lo
    f16x8 qhf[4], qlf[4];
    #pragma unroll
    for (int ks = 0; ks < 4; ++ks) {
        const unsigned* yp = ypk + (bq + fblk0 + col) * DPAD + ks * 16 + half * 8;
        unpack8(*(const uint4*)yp, *(const uint4*)(yp + 4), qhf[ks], qlf[ks]);
    }

    if (tid < GHALF) wssh[tid] = wv[bq + gstart + tid];

    // staging: 8 KB tile = 32 rows x 256 B. Per wave 2 x 16B per lane,
    // lane-contiguous LDS writes; source chunk = slot ^ (row&15) picks
    // xh/xl + offset (inverse swizzle, proven round-8 pattern).
    const int base = wid * 2048 + lane * 16;
    int rowj[2], soj[2];
    const unsigned short* sbj[2];
    #pragma unroll
    for (int j = 0; j < 2; ++j) {
        const int D = base + j * 1024;
        rowj[j] = D >> 8;
        const int c = ((D >> 4) & 15) ^ (rowj[j] & 15);
        sbj[j] = (c < 8) ? xh : xl;
        soj[j] = (c & 7) * 8;
    }

    uint4 st[2];
    #pragma unroll
    for (int j = 0; j < 2; ++j)
        st[j] = *(const uint4*)(sbj[j] + (bq + gstart + rowj[j]) * DPAD + soj[j]);

    float lsum = 0.f, asum = 0.f;

    for (int t = 0; t < NSTEP; ++t) {
        const int buf = t & 1;
        #pragma unroll
        for (int j = 0; j < 2; ++j)
            *(uint4*)(&Kt[buf][base + j * 1024]) = st[j];
        if (t + 1 < NSTEP) {
            const int gn = gstart + (t + 1) * GSTEP;
            #pragma unroll
            for (int j = 0; j < 2; ++j)
                st[j] = *(const uint4*)(sbj[j] + (bq + gn + rowj[j]) * DPAD + soj[j]);
        }
        __syncthreads();

        const int arow = col;
        const int rbase = arow << 8;
        const int ar15 = arow & 15;
        f32x16 acc;
        #pragma unroll
        for (int i = 0; i < 16; ++i) acc[i] = 0.f;
        #pragma unroll
        for (int ks = 0; ks < 4; ++ks) {
            const int ch = ks * 2 + half;
            f16x8 ahf = *(const f16x8*)(&Kt[buf][rbase + ((ch ^ ar15) << 4)]);
            f16x8 alf = *(const f16x8*)(&Kt[buf][rbase + (((8 + ch) ^ ar15) << 4)]);
            acc = __builtin_amdgcn_mfma_f32_32x32x16_f16(ahf, qlf[ks], acc, 0, 0, 0);
            acc = __builtin_amdgcn_mfma_f32_32x32x16_f16(alf, qhf[ks], acc, 0, 0, 0);
            acc = __builtin_amdgcn_mfma_f32_32x32x16_f16(ahf, qhf[ks], acc, 0, 0, 0);
        }
        // D row g = (reg&3) + 8*(reg>>2) + 4*half
        const float* wpb = wssh + t * GSTEP + 4 * half;
        #pragma unroll
        for (int q = 0; q < 4; ++q) {
            float4 w4 = *(const float4*)(wpb + q * 8);
            float p0 = exp2_fast(acc[q * 4 + 0]);
            float p1 = exp2_fast(acc[q * 4 + 1]);
            float p2 = exp2_fast(acc[q * 4 + 2]);
            float p3 = exp2_fast(acc[q * 4 + 3]);
            lsum += ((p0 + p1) + (p2 + p3));
            asum = fmaf(p0, w4.x, fmaf(p1, w4.y,
                   fmaf(p2, w4.z, fmaf(p3, w4.w, asum))));
        }
    }

    lsum += __shfl_xor(lsum, 32);
    asum += __shfl_xor(asum, 32);
    if (half == 0) {
        size_t o = ((size_t)sp * BB + b) * FF + fblk0 + col;
        partL[o] = lsum;
        partA[o] = asum;
    }
}

// ---------------------------------------------------------------------------
// bn: combine split partials, BatchNorm over batch per channel f.
// Grid 32 x 64 threads: spread the partial read over 32 CUs.
// ---------------------------------------------------------------------------
__global__ __launch_bounds__(64) void bn_kernel(
    const float* __restrict__ partL, const float* __restrict__ partA,
    const float* __restrict__ gamma, const float* __restrict__ beta,
    float* __restrict__ out)
{
    const int f = blockIdx.x * 64 + threadIdx.x;
    float v[BB];
    float mean = 0.f;
    #pragma unroll
    for (int b = 0; b < BB; ++b) {
        float l = 0.f, a = 0.f;
        #pragma unroll
        for (int s = 0; s < SPLIT; ++s) {
            l += partL[((size_t)s * BB + b) * FF + f];
            a += partA[((size_t)s * BB + b) * FF + f];
        }
        v[b] = a / l;
        mean += v[b];
    }
    mean *= (1.f / BB);
    float var = 0.f;
    #pragma unroll
    for (int b = 0; b < BB; ++b) {
        float d = v[b] - mean;
        var = fmaf(d, d, var);
    }
    var *= (1.f / BB);
    const float inv = rsqrtf(var + 1e-5f);
    const float g = gamma[f], be = beta[f];
    #pragma unroll
    for (int b = 0; b < BB; ++b)
        out[((size_t)b << 11) + f] = (v[b] - mean) * inv * g + be;
}

// ---------------------------------------------------------------------------
extern "C" void kernel_launch(void* const* d_in, const int* in_sizes, int n_in,
                              void* d_out, int out_size, void* d_ws, size_t ws_size,
                              hipStream_t stream)
{
    const float* x     = (const float*)d_in[0];
    const float* Wqkv  = (const float*)d_in[1];
    const float* Wout  = (const float*)d_in[2];
    // d_in[3] = b_out: cancels exactly under BatchNorm mean subtraction.
    const float* gamma = (const float*)d_in[4];
    const float* beta  = (const float*)d_in[5];

    char* wsb = (char*)d_ws;
    const size_t PANEL = (size_t)ROWS * DPAD * sizeof(unsigned short);  // 8 MB
    unsigned short* xh = (unsigned short*)(wsb);
    unsigned short* xl = (unsigned short*)(wsb + PANEL);
    unsigned*      ypk = (unsigned*)(wsb + 2 * PANEL);                  // 16 MB
    float*          wv = (float*)(wsb + 4 * PANEL);                     // 256 KB
    unsigned*     Mtpk = (unsigned*)(wsb + 4 * PANEL + 262144);         // 16 KB
    float*           u = (float*)(wsb + 4 * PANEL + 262144 + 16384);
    float*       partL = (float*)(wsb + 4 * PANEL + 262144 + 17408);
    float*       partA = partL + (size_t)SPLIT * BB * FF;
    // total ~= 36.3 MiB

    prep_kernel<<<dim3(17), dim3(256), 0, stream>>>(Wqkv, Wout, Mtpk, u);

    xymm_kernel<<<dim3(ROWS / 128), dim3(256), 0, stream>>>(
        x, Mtpk, u, xh, xl, ypk, wv);

    attn_kernel<<<dim3(BB * 16 * SPLIT), dim3(256), 0, stream>>>(
        xh, xl, ypk, wv, partL, partA);

    bn_kernel<<<dim3(FF / 64), dim3(64), 0, stream>>>(
        partL, partA, gamma, beta, (float*)d_out);
}

// Round 10
// 92.058 us; speedup vs baseline: 1.4743x; 1.4743x over previous
//
#include <hip/hip_runtime.h>
#include <math.h>

// Problem constants: B=32, F=2048, hw=49, A=1.
#define BB    32
#define FF    2048
#define HW    49
#define ROWS  (BB * FF)
#define DPAD  64
#define SPLIT 4
#define GSTEP 64
#define GHALF (FF / SPLIT)               // 512
#define NSTEP (GHALF / GSTEP)            // 8

typedef float f32x16 __attribute__((ext_vector_type(16)));
typedef _Float16 f16x8 __attribute__((ext_vector_type(8)));
typedef short s16x8 __attribute__((ext_vector_type(8)));

// exp2 via the amdgcn builtin -> single v_exp_f32, compiler-managed hazards.
__device__ inline float exp2_fast(float x) {
    return __builtin_amdgcn_exp2f(x);
}

// fp32 -> fp16 hi + fp16 lo (RNE), packed (hi<<16)|lo. Combined rel err ~2^-22.
__device__ inline unsigned f16pack(float v) {
    _Float16 h = (_Float16)v;
    _Float16 l = (_Float16)(v - (float)h);
    unsigned hb = (unsigned)__builtin_bit_cast(unsigned short, h);
    unsigned lb = (unsigned)__builtin_bit_cast(unsigned short, l);
    return (hb << 16) | lb;
}

__device__ inline void unpack8(uint4 a, uint4 b, f16x8& h, f16x8& l) {
    unsigned w[8] = {a.x, a.y, a.z, a.w, b.x, b.y, b.z, b.w};
    s16x8 hs, ls;
    #pragma unroll
    for (int i = 0; i < 8; ++i) {
        hs[i] = (short)(w[i] >> 16);
        ls[i] = (short)(w[i] & 0xFFFFu);
    }
    h = __builtin_bit_cast(f16x8, hs);
    l = __builtin_bit_cast(f16x8, ls);
}

// ---------------------------------------------------------------------------
// prep: M[j,d] = sum_e Wq[e,j] Wk[e,d] * log2(e)/7 -> Mtpk[d][j] (fp16 hi/lo)
//       u[d]   = sum_e Wv[e,d] * Wout[e]
// Scores come out in the log2 domain; softmax probs = exp2(s) = e^(q.k/7).
// ---------------------------------------------------------------------------
__global__ __launch_bounds__(256) void prep_kernel(
    const float* __restrict__ Wqkv, const float* __restrict__ Wout,
    unsigned* __restrict__ Mtpk, float* __restrict__ u)
{
    __shared__ float W2[98][52];
    const int tid = threadIdx.x;
    if (blockIdx.x < 16) {
        for (int i = tid; i < 98 * 52; i += 256) {
            int e = i / 52, j = i - e * 52;
            W2[e][j] = (j < HW) ? Wqkv[e * HW + j] : 0.f;
        }
        __syncthreads();
        const int d = blockIdx.x * 4 + (tid >> 6);
        const int j = tid & 63;
        float s = 0.f;
        if (d < HW && j < HW) {
            for (int e = 0; e < HW; ++e) s = fmaf(W2[e][j], W2[49 + e][d], s);
            s *= 0.2060992915555662f;      // log2(e) / 7
        }
        Mtpk[d * 64 + j] = f16pack(s);
    } else {
        if (tid < 64) {
            float s = 0.f;
            if (tid < HW)
                for (int e = 0; e < HW; ++e)
                    s = fmaf(Wqkv[(98 + e) * HW + tid], Wout[e], s);
            u[tid] = s;
        }
    }
}

// ---------------------------------------------------------------------------
// xymm: per 128 rows: coalesced x load via LDS bounce, x hi fp16 panel xh,
// w = x.u, y = x.M (3-MFMA fp16 hi/lo) -> packed u32 panel ypk.
// XCD-affinity swizzle: XCD k produces b in [4k, 4k+4) -- the same b's that
// attn's XCD k consumes, keeping panels in the producing XCD's L2.
// ---------------------------------------------------------------------------
__global__ __launch_bounds__(256) void xymm_kernel(
    const float* __restrict__ x, const unsigned* __restrict__ Mtpk,
    const float* __restrict__ u,
    unsigned short* __restrict__ xh,
    unsigned* __restrict__ ypk, float* __restrict__ wv)
{
    __shared__ float xsh[128 * HW];
    __shared__ float ush[64];
    const int blk = (blockIdx.x & 7) * 64 + (blockIdx.x >> 3);   // affinity map
    const int tid = threadIdx.x, lane = tid & 63, wid = tid >> 6;
    const int col = lane & 31, half = lane >> 5;
    if (tid < 64) ush[tid] = u[tid];

    {
        const float* xb = x + (size_t)blk * 128 * HW;
        for (int i = tid; i < 128 * HW; i += 256) xsh[i] = xb[i];
    }
    __syncthreads();

    const int rloc = wid * 32 + col;
    const int row = blk * 128 + rloc;

    f16x8 ah[4], al[4];
    float wp = 0.f;
    #pragma unroll
    for (int ks = 0; ks < 4; ++ks) {
        s16x8 hs, ls;
        #pragma unroll
        for (int i = 0; i < 8; ++i) {
            int d = ks * 16 + half * 8 + i;
            float t = (d < HW) ? xsh[rloc * HW + d] : 0.f;
            wp = fmaf(t, ush[d], wp);
            _Float16 h = (_Float16)t;
            _Float16 l = (_Float16)(t - (float)h);
            hs[i] = __builtin_bit_cast(short, h);
            ls[i] = __builtin_bit_cast(short, l);
        }
        ah[ks] = __builtin_bit_cast(f16x8, hs);
        al[ks] = __builtin_bit_cast(f16x8, ls);
        const size_t o = (size_t)row * DPAD + ks * 16 + half * 8;
        *(f16x8*)(xh + o) = ah[ks];
    }
    wp += __shfl_xor(wp, 32);
    if (half == 0) wv[row] = wp;

    const int r0 = blk * 128 + wid * 32;
    for (int dt = 0; dt < 2; ++dt) {
        f16x8 mh[4], ml[4];
        #pragma unroll
        for (int ks = 0; ks < 4; ++ks) {
            const unsigned* mp = Mtpk + (dt * 32 + col) * 64 + ks * 16 + half * 8;
            unpack8(*(const uint4*)mp, *(const uint4*)(mp + 4), mh[ks], ml[ks]);
        }
        f32x16 acc;
        #pragma unroll
        for (int i = 0; i < 16; ++i) acc[i] = 0.f;
        #pragma unroll
        for (int ks = 0; ks < 4; ++ks) {
            acc = __builtin_amdgcn_mfma_f32_32x32x16_f16(ah[ks], ml[ks], acc, 0, 0, 0);
            acc = __builtin_amdgcn_mfma_f32_32x32x16_f16(al[ks], mh[ks], acc, 0, 0, 0);
            acc = __builtin_amdgcn_mfma_f32_32x32x16_f16(ah[ks], mh[ks], acc, 0, 0, 0);
        }
        #pragma unroll
        for (int reg = 0; reg < 16; ++reg) {
            int drow = (reg & 3) + 8 * (reg >> 2) + 4 * half;
            ypk[(size_t)(r0 + drow) * DPAD + dt * 32 + col] = f16pack(acc[reg]);
        }
    }
}

// ---------------------------------------------------------------------------
// attn: scores(log2) = y . xh^T, 2 MFMAs per ks (x hi-only; y hi+lo), no-max
// softmax via v_exp_f32, scalar value w. Block: 4 waves x 32 f-cols,
// GHALF=512 g-rows, K-tile 64 rows (2 x 4KB halves) double-buffered.
// Grid 2048 = one fully-resident cohort (8 blocks/CU); per-XCD working set
// = 4 b x (xh 256K + ypk 512K) = 3 MB -> local-L2-resident (affinity with
// xymm's swizzle).
// ---------------------------------------------------------------------------
__global__ __launch_bounds__(256, 4) void attn_kernel(
    const unsigned short* __restrict__ xh,
    const unsigned* __restrict__ ypk, const float* __restrict__ wv,
    float* __restrict__ partL, float* __restrict__ partA)
{
    __shared__ __align__(16) unsigned char Kt[2][GSTEP * 128];   // 2 x 8 KB
    __shared__ __align__(16) float wssh[GHALF];                  // 2 KB

    // XCD-chunked swizzle: 2048 blocks, 256 logical per XCD -> b in [4k,4k+4).
    const int bid = blockIdx.x;
    const int L = (bid & 7) * 256 + (bid >> 3);
    const int b   = L >> 6;
    const int r63 = L & 63;
    const int ftg = r63 >> 2;       // 0..15
    const int sp  = r63 & 3;        // 0..3

    const int tid  = threadIdx.x;
    const int lane = tid & 63;
    const int wid  = tid >> 6;
    const int col  = lane & 31;
    const int half = lane >> 5;
    const int fblk0  = ftg * 128 + wid * 32;
    const int gstart = sp * GHALF;
    const size_t bq = (size_t)b * FF;

    // hoist y fragments (B operand, col = fblk0+col), unpack hi/lo
    f16x8 qhf[4], qlf[4];
    #pragma unroll
    for (int ks = 0; ks < 4; ++ks) {
        const unsigned* yp = ypk + (bq + fblk0 + col) * DPAD + ks * 16 + half * 8;
        unpack8(*(const uint4*)yp, *(const uint4*)(yp + 4), qhf[ks], qlf[ks]);
    }

    for (int i = tid; i < GHALF; i += 256) wssh[i] = wv[bq + gstart + i];

    // staging: 8 KB = 64 rows x 128 B; thread t writes 16B at D = t*16 (+4096),
    // LDS row = D>>7, slot s = (D>>4)&7; source chunk c = s ^ (row&7)
    // (inverse swizzle on the global address; LDS writes lane-contiguous).
    int rowj[2], soj[2];
    #pragma unroll
    for (int j = 0; j < 2; ++j) {
        const int D = tid * 16 + j * 4096;
        rowj[j] = D >> 7;
        const int c = ((D >> 4) & 7) ^ (rowj[j] & 7);
        soj[j] = c * 8;                          // shorts
    }

    uint4 st[2];
    #pragma unroll
    for (int j = 0; j < 2; ++j)
        st[j] = *(const uint4*)(xh + (bq + gstart + rowj[j]) * DPAD + soj[j]);

    float lsum = 0.f, asum = 0.f;

    for (int t = 0; t < NSTEP; ++t) {
        const int buf = t & 1;
        *(uint4*)(&Kt[buf][tid * 16])        = st[0];
        *(uint4*)(&Kt[buf][tid * 16 + 4096]) = st[1];
        if (t + 1 < NSTEP) {
            const int gn = gstart + (t + 1) * GSTEP;
            #pragma unroll
            for (int j = 0; j < 2; ++j)
                st[j] = *(const uint4*)(xh + (bq + gn + rowj[j]) * DPAD + soj[j]);
        }
        __syncthreads();

        #pragma unroll
        for (int gsub = 0; gsub < 2; ++gsub) {
            const int rbase = gsub * 4096 + col * 128;
            const int a7 = col & 7;
            f32x16 acc;
            #pragma unroll
            for (int i = 0; i < 16; ++i) acc[i] = 0.f;
            #pragma unroll
            for (int ks = 0; ks < 4; ++ks) {
                const int c = ks * 2 + half;
                f16x8 ahf = *(const f16x8*)(&Kt[buf][rbase + ((c ^ a7) << 4)]);
                acc = __builtin_amdgcn_mfma_f32_32x32x16_f16(ahf, qlf[ks], acc, 0, 0, 0);
                acc = __builtin_amdgcn_mfma_f32_32x32x16_f16(ahf, qhf[ks], acc, 0, 0, 0);
            }
            // D row g = (reg&3) + 8*(reg>>2) + 4*half
            const float* wpb = wssh + t * GSTEP + gsub * 32 + 4 * half;
            #pragma unroll
            for (int q = 0; q < 4; ++q) {
                float4 w4 = *(const float4*)(wpb + q * 8);
                float p0 = exp2_fast(acc[q * 4 + 0]);
                float p1 = exp2_fast(acc[q * 4 + 1]);
                float p2 = exp2_fast(acc[q * 4 + 2]);
                float p3 = exp2_fast(acc[q * 4 + 3]);
                lsum += ((p0 + p1) + (p2 + p3));
                asum = fmaf(p0, w4.x, fmaf(p1, w4.y,
                       fmaf(p2, w4.z, fmaf(p3, w4.w, asum))));
            }
        }
    }

    lsum += __shfl_xor(lsum, 32);
    asum += __shfl_xor(asum, 32);
    if (half == 0) {
        size_t o = ((size_t)sp * BB + b) * FF + fblk0 + col;
        partL[o] = lsum;
        partA[o] = asum;
    }
}

// ---------------------------------------------------------------------------
// bn: combine split partials, BatchNorm over batch per channel f.
// ---------------------------------------------------------------------------
__global__ __launch_bounds__(64) void bn_kernel(
    const float* __restrict__ partL, const float* __restrict__ partA,
    const float* __restrict__ gamma, const float* __restrict__ beta,
    float* __restrict__ out)
{
    const int f = blockIdx.x * 64 + threadIdx.x;
    float v[BB];
    float mean = 0.f;
    #pragma unroll
    for (int b = 0; b < BB; ++b) {
        float l = 0.f, a = 0.f;
        #pragma unroll
        for (int s = 0; s < SPLIT; ++s) {
            l += partL[((size_t)s * BB + b) * FF + f];
            a += partA[((size_t)s * BB + b) * FF + f];
        }
        v[b] = a / l;
        mean += v[b];
    }
    mean *= (1.f / BB);
    float var = 0.f;
    #pragma unroll
    for (int b = 0; b < BB; ++b) {
        float d = v[b] - mean;
        var = fmaf(d, d, var);
    }
    var *= (1.f / BB);
    const float inv = rsqrtf(var + 1e-5f);
    const float g = gamma[f], be = beta[f];
    #pragma unroll
    for (int b = 0; b < BB; ++b)
        out[((size_t)b << 11) + f] = (v[b] - mean) * inv * g + be;
}

// ---------------------------------------------------------------------------
extern "C" void kernel_launch(void* const* d_in, const int* in_sizes, int n_in,
                              void* d_out, int out_size, void* d_ws, size_t ws_size,
                              hipStream_t stream)
{
    const float* x     = (const float*)d_in[0];
    const float* Wqkv  = (const float*)d_in[1];
    const float* Wout  = (const float*)d_in[2];
    // d_in[3] = b_out: cancels exactly under BatchNorm mean subtraction.
    const float* gamma = (const float*)d_in[4];
    const float* beta  = (const float*)d_in[5];

    char* wsb = (char*)d_ws;
    const size_t PANEL = (size_t)ROWS * DPAD * sizeof(unsigned short);  // 8 MB
    unsigned short* xh = (unsigned short*)(wsb);
    unsigned*      ypk = (unsigned*)(wsb + PANEL);                      // 16 MB
    float*          wv = (float*)(wsb + 3 * PANEL);                     // 256 KB
    unsigned*     Mtpk = (unsigned*)(wsb + 3 * PANEL + 262144);         // 16 KB
    float*           u = (float*)(wsb + 3 * PANEL + 262144 + 16384);
    float*       partL = (float*)(wsb + 3 * PANEL + 262144 + 17408);
    float*       partA = partL + (size_t)SPLIT * BB * FF;
    // total ~= 26.3 MiB

    prep_kernel<<<dim3(17), dim3(256), 0, stream>>>(Wqkv, Wout, Mtpk, u);

    xymm_kernel<<<dim3(ROWS / 128), dim3(256), 0, stream>>>(
        x, Mtpk, u, xh, ypk, wv);

    attn_kernel<<<dim3(BB * 16 * SPLIT), dim3(256), 0, stream>>>(
        xh, ypk, wv, partL, partA);

    bn_kernel<<<dim3(FF / 64), dim3(64), 0, stream>>>(
        partL, partA, gamma, beta, (float*)d_out);
}